// Round 2
// baseline (1714.707 us; speedup 1.0000x reference)
//
#include <hip/hip_runtime.h>
#include <hip/hip_bf16.h>

// Hete_MLP2_atten: fused  tanh(x@W1+b1)@W2 -> softmax over m -> weighted sum
// M=8 meta paths, D=256, H=128; N from in_sizes[0].
// One wave = 16 nodes (MFMA 16x16x32 bf16 A-rows). Online exp-weighted
// accumulation over m (no max subtraction: |logit| <= sum|W2| ~ 9).
// b2 dropped (cancels in softmax).

typedef __attribute__((ext_vector_type(8))) short short8;
typedef __attribute__((ext_vector_type(4))) int   int4v;
typedef __attribute__((ext_vector_type(4))) float f32x4;

#define DDIM  256
#define HDIM  128
#define MMETA 8

// fp32 -> bf16 round-to-nearest-even, pure integer ops (trivially copyable)
__device__ __forceinline__ unsigned f2bf_u(float f) {
    unsigned u = __builtin_bit_cast(unsigned, f);
    u += 0x7fffu + ((u >> 16) & 1u);
    return u >> 16;
}
__device__ __forceinline__ unsigned pk2bf(float a, float b) {
    return f2bf_u(a) | (f2bf_u(b) << 16);
}
__device__ __forceinline__ float bf2f(short s) {
    unsigned u = ((unsigned)(unsigned short)s) << 16;
    return __builtin_bit_cast(float, u);
}

__global__ __launch_bounds__(256, 2) void hete_mlp2_atten_kernel(
    const float* __restrict__ homo,  // [M,N,D]
    const float* __restrict__ W1,    // [D,H] row-major (h contiguous)
    const float* __restrict__ b1,    // [H]
    const float* __restrict__ W2,    // [H]
    float* __restrict__ out,         // [N,D]
    int N)
{
    // W1 bf16 frags, frag-ordered: chunk c=t*8+s, lane l holds
    // B[k = s*32 + (l>>4)*8 + j][h = t*16 + (l&15)], j=0..7 (16B per lane)
    __shared__ __attribute__((aligned(16))) short w1f[64 * 64 * 8]; // 64 KB

    const int tid  = threadIdx.x;
    const int lane = tid & 63;
    const int wave = tid >> 6;
    const int colq = lane & 15;   // A-row (node) for loads; h-col in C layout
    const int quad = lane >> 4;

    const int  node   = blockIdx.x * 64 + wave * 16 + colq;
    const bool valid  = node < N;
    const int  nclamp = valid ? node : (N - 1);

    const size_t mstride = (size_t)N * DDIM;
    const float* xp0 = homo + (size_t)nclamp * DDIM + quad * 8;

    // issue first x-tile loads early (independent of LDS fill)
    float4 xf[16];
#pragma unroll
    for (int s = 0; s < 8; ++s) {
        xf[2*s]   = *(const float4*)(xp0 + s*32);
        xf[2*s+1] = *(const float4*)(xp0 + s*32 + 4);
    }

    // per-lane bias / W2 for h-column t*16+colq (matches C/D col = lane&15)
    float b1v[8], w2v[8];
#pragma unroll
    for (int t = 0; t < 8; ++t) {
        b1v[t] = b1[t*16 + colq];
        w2v[t] = W2[t*16 + colq];
    }

    // ---- build W1 bf16 frags in LDS (once per block) ----
    // wave w handles chunks c == w (mod 4); reads are 64B-line coalesced
    {
#pragma unroll
        for (int i = 0; i < 16; ++i) {
            int c = wave + i*4;
            int t = c >> 3, s = c & 7;
            int k0 = s*32 + quad*8;
            int h  = t*16 + colq;
            const float* wp = W1 + (size_t)k0 * HDIM + h;
            float v[8];
#pragma unroll
            for (int j = 0; j < 8; ++j) v[j] = wp[j * HDIM];
            int4v p;
            p.x = (int)pk2bf(v[0], v[1]); p.y = (int)pk2bf(v[2], v[3]);
            p.z = (int)pk2bf(v[4], v[5]); p.w = (int)pk2bf(v[6], v[7]);
            *(int4v*)&w1f[(c*64 + lane)*8] = p;   // ds_write_b128, conflict-free
        }
    }
    __syncthreads();

    const short* wbase = &w1f[lane * 8];

    float acc[64];        // node = colq, d = s*32 + quad*8 + j
#pragma unroll
    for (int i = 0; i < 64; ++i) acc[i] = 0.f;
    float S = 0.f;

#pragma unroll 1
    for (int m = 0; m < MMETA; ++m) {
        // convert current x-tile to bf16 A-frags
        short8 a[8];
#pragma unroll
        for (int s = 0; s < 8; ++s) {
            int4v p;
            float4 lo = xf[2*s], hi = xf[2*s+1];
            p.x = (int)pk2bf(lo.x, lo.y); p.y = (int)pk2bf(lo.z, lo.w);
            p.z = (int)pk2bf(hi.x, hi.y); p.w = (int)pk2bf(hi.z, hi.w);
            a[s] = __builtin_bit_cast(short8, p);
        }
        // prefetch next m's x-tile (in flight across MFMA/tanh/acc phases)
        if (m != MMETA - 1) {
            const float* xn = xp0 + (size_t)(m + 1) * mstride;
#pragma unroll
            for (int s = 0; s < 8; ++s) {
                xf[2*s]   = *(const float4*)(xn + s*32);
                xf[2*s+1] = *(const float4*)(xn + s*32 + 4);
            }
        }
        // h = x @ W1 : [16 nodes x 128 h], K=256 in 8 steps
        f32x4 acch[8];
#pragma unroll
        for (int t = 0; t < 8; ++t) acch[t] = (f32x4){0.f, 0.f, 0.f, 0.f};
#pragma unroll
        for (int s = 0; s < 8; ++s) {
#pragma unroll
            for (int t = 0; t < 8; ++t) {
                short8 bfr = *(const short8*)(wbase + (t*8 + s)*512); // ds_read_b128
                acch[t] = __builtin_amdgcn_mfma_f32_16x16x32_bf16(a[s], bfr, acch[t], 0, 0, 0);
            }
        }
        // tanh(h + b1) . W2  -> partial logits; C layout: row(node)=quad*4+r, col(h)=colq
        float pr[4] = {0.f, 0.f, 0.f, 0.f};
#pragma unroll
        for (int t = 0; t < 8; ++t) {
#pragma unroll
            for (int r = 0; r < 4; ++r) {
                float v = acch[t][r] + b1v[t];
                v = fminf(fmaxf(v, -15.f), 15.f);       // guard exp overflow -> NaN
                float e  = __expf(2.f * v);
                float th = (e - 1.f) * __builtin_amdgcn_rcpf(e + 1.f);
                pr[r] = fmaf(th, w2v[t], pr[r]);
            }
        }
        // reduce over 16 h-col lanes within each quad (xor butterfly)
#pragma unroll
        for (int mask = 1; mask <= 8; mask <<= 1) {
#pragma unroll
            for (int r = 0; r < 4; ++r) pr[r] += __shfl_xor(pr[r], mask);
        }
        // redistribute: lane needs logit of node v=colq; donor lane (v>>2)*16 + (v&3)
        const int l3 = lane & 3;
        float p01 = (l3 & 1) ? pr[1] : pr[0];
        float p23 = (l3 & 1) ? pr[3] : pr[2];
        float expose = (l3 & 2) ? p23 : p01;     // = pr[lane&3]
        float logit  = __shfl(expose, ((lane >> 2) & 3) * 16 + l3);
        float w = __expf(logit);                 // no max-sub: |logit| <= ~9
        S += w;
        // acc += w * x_m  (bf16 x, fp32 acc)
#pragma unroll
        for (int s = 0; s < 8; ++s) {
#pragma unroll
            for (int j = 0; j < 8; ++j) {
                acc[s*8 + j] = fmaf(w, bf2f(a[s][j]), acc[s*8 + j]);
            }
        }
    }

    if (valid) {
        float rinv = 1.f / S;
        float* op = out + (size_t)node * DDIM + quad * 8;
#pragma unroll
        for (int s = 0; s < 8; ++s) {
            float4 o0, o1;
            o0.x = acc[s*8+0]*rinv; o0.y = acc[s*8+1]*rinv;
            o0.z = acc[s*8+2]*rinv; o0.w = acc[s*8+3]*rinv;
            o1.x = acc[s*8+4]*rinv; o1.y = acc[s*8+5]*rinv;
            o1.z = acc[s*8+6]*rinv; o1.w = acc[s*8+7]*rinv;
            *(float4*)(op + s*32)     = o0;
            *(float4*)(op + s*32 + 4) = o1;
        }
    }
}

extern "C" void kernel_launch(void* const* d_in, const int* in_sizes, int n_in,
                              void* d_out, int out_size, void* d_ws, size_t ws_size,
                              hipStream_t stream) {
    // inputs: 0=nodes(int32,N, unused) 1=homo(f32,M*N*D) 2=W1(f32,D*H)
    //         3=b1(f32,H) 4=W2(f32,H) 5=b2(f32,1, cancels in softmax)
    const float* homo = (const float*)d_in[1];
    const float* W1   = (const float*)d_in[2];
    const float* b1   = (const float*)d_in[3];
    const float* W2   = (const float*)d_in[4];
    float* out = (float*)d_out;
    const int N = in_sizes[0];
    const int grid = (N + 63) / 64;   // 64 nodes per 256-thread block (16/wave)
    hipLaunchKernelGGL(hete_mlp2_atten_kernel, dim3(grid), dim3(256), 0, stream,
                       homo, W1, b1, W2, out, N);
}